// Round 11
// baseline (267.495 us; speedup 1.0000x reference)
//
#include <hip/hip_runtime.h>
#include <hip/hip_bf16.h>

#define TT 7
#define CCH 128
#define ICH 64
#define NHW 4096
#define NSPLIT 4
#define MCHUNK (NHW/NSPLIT)

typedef __attribute__((ext_vector_type(8))) short short8;
typedef __attribute__((ext_vector_type(4))) short sshort4;
typedef __attribute__((ext_vector_type(4))) float floatx4;

#define LOG2E 1.44269504f

static __device__ __forceinline__ short f2bf(float f){
  __hip_bfloat16 h = __float2bfloat16(f);
  return *reinterpret_cast<short*>(&h);
}
static __device__ __forceinline__ float bf2f(short s){
  __hip_bfloat16 h = *reinterpret_cast<__hip_bfloat16*>(&s);
  return __bfloat162float(h);
}

// ---------------- fused cast+stats: xbf[t][n][c] bf16; per-block stat partials
// spart/spart2 layout: [nx][224] (group = t*32 + zh*16 + w*4 + g) — no memset needed.
__global__ __launch_bounds__(256) void k_precast(const float* __restrict__ x,
    __hip_bfloat16* __restrict__ xbf, float* __restrict__ spart, float* __restrict__ spart2){
  __shared__ short tile[64][66];
  int t = blockIdx.y, n0 = blockIdx.x*64, zh = blockIdx.z;
  int ln = threadIdx.x & 63, w = threadIdx.x >> 6;
  float sl[4] = {0.f,0.f,0.f,0.f}, s2l[4] = {0.f,0.f,0.f,0.f};
  #pragma unroll 4
  for (int ci = 0; ci < 16; ++ci){
    int cl = w*16 + ci;
    float v = x[((size_t)t*CCH + zh*64 + cl)*NHW + n0 + ln];
    tile[ln][cl] = f2bf(v);
    sl[ci>>2]  += v;
    s2l[ci>>2] += v*v;
  }
  #pragma unroll
  for (int off = 32; off; off >>= 1){
    #pragma unroll
    for (int g = 0; g < 4; ++g){
      sl[g]  += __shfl_xor(sl[g],  off);
      s2l[g] += __shfl_xor(s2l[g], off);
    }
  }
  if (ln == 0){
    float* sp  = spart  + (size_t)blockIdx.x*224 + t*32 + zh*16 + w*4;
    float* sp2 = spart2 + (size_t)blockIdx.x*224 + t*32 + zh*16 + w*4;
    #pragma unroll
    for (int g = 0; g < 4; ++g){ sp[g] = sl[g]; sp2[g] = s2l[g]; }
  }
  __syncthreads();
  int row = threadIdx.x >> 2, seg = threadIdx.x & 3;
  short* dst = reinterpret_cast<short*>(xbf) + ((size_t)t*NHW + n0 + row)*CCH + zh*64 + seg*16;
  #pragma unroll
  for (int k = 0; k < 2; ++k){
    short8 v;
    #pragma unroll
    for (int j = 0; j < 8; ++j) v[j] = tile[row][seg*16 + k*8 + j];
    *reinterpret_cast<short8*>(dst + k*8) = v;
  }
}

// ---------------- setup: GN-fold (theta scaled by LOG2E) + wz/mb prep
__global__ __launch_bounds__(256) void k_setup(
    const float* __restrict__ gw, const float* __restrict__ gb,
    const float* __restrict__ thw, const float* __restrict__ thb,
    const float* __restrict__ phw, const float* __restrict__ phb,
    const float* __restrict__ gamma, const float* __restrict__ beta,
    const float* __restrict__ spart, const float* __restrict__ spart2,
    __hip_bfloat16* __restrict__ Wth, float* __restrict__ bth,
    __hip_bfloat16* __restrict__ Wg,  float* __restrict__ bg,
    __hip_bfloat16* __restrict__ Wphi, float* __restrict__ bphi,
    const float* __restrict__ wz, const float* __restrict__ wz1,
    const float* __restrict__ wz_b, const float* __restrict__ wz1_b,
    const float* __restrict__ mb,
    __hip_bfloat16* __restrict__ wzcat, float* __restrict__ biasz,
    __hip_bfloat16* __restrict__ mbT, __hip_bfloat16* __restrict__ mbbf){
  if (blockIdx.x < 240){
    int w = threadIdx.x >> 6, lane = threadIdx.x & 63;
    int oidx = blockIdx.x*4 + w;
    const float *W, *B; __hip_bfloat16 *Wf; float *bfo; int t, o;
    float scale = 1.f;
    if (oidx < 448){ t = oidx >> 6; o = oidx & 63; W = thw; B = thb; Wf = Wth + ((size_t)t*ICH + o)*CCH; bfo = bth + t*64 + o; scale = LOG2E; }
    else if (oidx < 896){ int j = oidx - 448; t = j >> 6; o = j & 63; W = gw; B = gb; Wf = Wg + ((size_t)t*ICH + o)*CCH; bfo = bg + t*64 + o; }
    else { t = 3; o = oidx - 896; W = phw; B = phb; Wf = Wphi + (size_t)o*CCH; bfo = bphi + o; }
    // per-lane group stats (sum 64 per-block partials; mostly broadcast loads)
    float mv[2], rv[2];
    #pragma unroll
    for (int h = 0; h < 2; ++h){
      int gid = t*32 + ((h*64 + lane) >> 2);
      float S = 0.f, S2 = 0.f;
      for (int i = 0; i < 64; ++i){
        S  += spart [(size_t)i*224 + gid];
        S2 += spart2[(size_t)i*224 + gid];
      }
      float m  = S * (1.f/16384.f);
      float vr = S2 * (1.f/16384.f) - m*m;
      mv[h] = m;
      rv[h] = rsqrtf(vr + 1e-6f);
    }
    float bp = 0.f;
    #pragma unroll
    for (int h = 0; h < 2; ++h){
      int c = h*64 + lane;
      float a  = gamma[c]*rv[h];
      float wv = W[o*CCH + c];
      Wf[c] = __float2bfloat16(wv * a * scale);
      bp += wv * (beta[c] - mv[h]*a);
    }
    #pragma unroll
    for (int off = 32; off; off >>= 1) bp += __shfl_xor(bp, off);
    if (lane == 0) *bfo = (bp + B[o]) * scale;
  } else {
    int idx = (blockIdx.x - 240)*256 + threadIdx.x;   // 0..32767
    #pragma unroll
    for (int k = 0; k < 2; ++k){
      int i = idx + k*32768;
      int o = i >> 9, kk = i & 511;
      float v = (kk < 448) ? wz[o*448 + kk] : wz1[o*64 + (kk-448)];
      wzcat[i] = __float2bfloat16(v);
    }
    if (idx < 128) biasz[idx] = wz_b[idx] + wz1_b[idx];
    if (idx < 64*256){
      int c = idx >> 8, j = idx & 255;
      float v = mb[idx];
      mbbf[idx] = __float2bfloat16(v);
      mbT[j*64 + c] = __float2bfloat16(v);
    }
  }
}

// ---------------- conv1x1 via MFMA, split z: 0 = theta(+phi), 1 = g
__global__ __launch_bounds__(256) void k_conv(const __hip_bfloat16* __restrict__ xbf,
    const __hip_bfloat16* __restrict__ Wth, const float* __restrict__ bth,
    const __hip_bfloat16* __restrict__ Wg,  const float* __restrict__ bg,
    const __hip_bfloat16* __restrict__ Wphi, const float* __restrict__ bphi,
    __hip_bfloat16* __restrict__ thetaT, __hip_bfloat16* __restrict__ g_nat,
    __hip_bfloat16* __restrict__ phi_bf){
  const int t = blockIdx.y, n0 = blockIdx.x*64, job = blockIdx.z;
  const int w = threadIdx.x >> 6, lane = threadIdx.x & 63;
  const int l15 = lane & 15, quad = lane >> 4;

  const short* xb = reinterpret_cast<const short*>(xbf) + ((size_t)t*NHW + n0)*CCH;
  short8 B[4][4];
  #pragma unroll
  for (int nt = 0; nt < 4; ++nt)
    #pragma unroll
    for (int kk = 0; kk < 4; ++kk)
      B[nt][kk] = *reinterpret_cast<const short8*>(xb + (size_t)(nt*16 + l15)*CCH + kk*32 + quad*8);

  if (job == 0){
    { // theta
      const short* aw = reinterpret_cast<const short*>(Wth) + ((size_t)t*ICH + w*16 + l15)*CCH + quad*8;
      short8 A[4];
      #pragma unroll
      for (int kk = 0; kk < 4; ++kk) A[kk] = *reinterpret_cast<const short8*>(aw + kk*32);
      float4 bv = *reinterpret_cast<const float4*>(bth + t*64 + w*16 + quad*4);
      #pragma unroll
      for (int nt = 0; nt < 4; ++nt){
        floatx4 acc = (floatx4){0.f,0.f,0.f,0.f};
        #pragma unroll
        for (int kk = 0; kk < 4; ++kk) acc = __builtin_amdgcn_mfma_f32_16x16x32_bf16(A[kk], B[nt][kk], acc, 0, 0, 0);
        sshort4 pk;
        pk[0] = f2bf(acc[0] + bv.x); pk[1] = f2bf(acc[1] + bv.y);
        pk[2] = f2bf(acc[2] + bv.z); pk[3] = f2bf(acc[3] + bv.w);
        short* dst = reinterpret_cast<short*>(thetaT) + ((size_t)t*NHW + n0 + nt*16 + l15)*ICH + w*16 + quad*4;
        *reinterpret_cast<sshort4*>(dst) = pk;
      }
    }
    if (t == 3){ // phi
      const short* aw = reinterpret_cast<const short*>(Wphi) + (size_t)(w*16 + l15)*CCH + quad*8;
      short8 A[4];
      #pragma unroll
      for (int kk = 0; kk < 4; ++kk) A[kk] = *reinterpret_cast<const short8*>(aw + kk*32);
      float4 bv = *reinterpret_cast<const float4*>(bphi + w*16 + quad*4);
      #pragma unroll
      for (int nt = 0; nt < 4; ++nt){
        floatx4 acc = (floatx4){0.f,0.f,0.f,0.f};
        #pragma unroll
        for (int kk = 0; kk < 4; ++kk) acc = __builtin_amdgcn_mfma_f32_16x16x32_bf16(A[kk], B[nt][kk], acc, 0, 0, 0);
        sshort4 pk;
        pk[0] = f2bf(acc[0] + bv.x); pk[1] = f2bf(acc[1] + bv.y);
        pk[2] = f2bf(acc[2] + bv.z); pk[3] = f2bf(acc[3] + bv.w);
        short* dst = reinterpret_cast<short*>(phi_bf) + (size_t)(n0 + nt*16 + l15)*ICH + w*16 + quad*4;
        *reinterpret_cast<sshort4*>(dst) = pk;
      }
    }
  } else { // g
    const short* aw = reinterpret_cast<const short*>(Wg) + ((size_t)t*ICH + w*16 + l15)*CCH + quad*8;
    short8 A[4];
    #pragma unroll
    for (int kk = 0; kk < 4; ++kk) A[kk] = *reinterpret_cast<const short8*>(aw + kk*32);
    float4 bv = *reinterpret_cast<const float4*>(bg + t*64 + w*16 + quad*4);
    #pragma unroll
    for (int nt = 0; nt < 4; ++nt){
      floatx4 acc = (floatx4){0.f,0.f,0.f,0.f};
      #pragma unroll
      for (int kk = 0; kk < 4; ++kk) acc = __builtin_amdgcn_mfma_f32_16x16x32_bf16(A[kk], B[nt][kk], acc, 0, 0, 0);
      short* gb = reinterpret_cast<short*>(g_nat);
      float bvv[4] = {bv.x, bv.y, bv.z, bv.w};
      #pragma unroll
      for (int r = 0; r < 4; ++r)
        gb[((size_t)t*ICH + w*16 + quad*4 + r)*NHW + n0 + nt*16 + l15] = f2bf(acc[r] + bvv[r]);
    }
  }
}

// ---------------- split-K flash attention (theta pre-scaled so p=exp2(s))
// Opart[(t,sp)][c][n] fp32 full-line stores; Zpart[(t,sp)][n]
// NOTE on launch bounds: total (VGPR+AGPR) live set ~96-102. Bound 4 (budget 128)
// is proven safe (VGPR 64, FETCH 29MB). Bound 6 (85) and 8 (64) SPILL catastrophically
// (R9: 395MB FETCH; R5: 1.9GB). Trying bound 5 (budget ~102): if FETCH balloons,
// revert to 4.
__global__ __launch_bounds__(256, 5) void k_attn(
    const __hip_bfloat16* __restrict__ phi_bf,   // [n][64]
    const __hip_bfloat16* __restrict__ thetaT,   // [t][m][64] (xLOG2E)
    const __hip_bfloat16* __restrict__ g_nat,    // [t][c][m]
    const float* __restrict__ stdp,
    float* __restrict__ Opart, float* __restrict__ Zpart)
{
  const int t    = blockIdx.z;
  const int sp   = blockIdx.y;
  const int w    = threadIdx.x >> 6;
  const int lane = threadIdx.x & 63;
  const int l15  = lane & 15;
  const int quad = lane >> 4;
  const int n0   = blockIdx.x*64;
  const int yn   = blockIdx.x;

  __shared__ short Plds[2][64][72];   // [buf][n][m + pad]
  __shared__ float Zsh[4][64];

  const float sstd  = stdp[0];
  const float coefL = -0.5f / (sstd*sstd) * LOG2E;

  const short* phi_s = reinterpret_cast<const short*>(phi_bf);
  const short* th_s  = reinterpret_cast<const short*>(thetaT) + (size_t)t*NHW*ICH;
  const short* g_s   = reinterpret_cast<const short*>(g_nat)  + (size_t)t*ICH*NHW;

  // phi B-frags for ALL 64 n (loop-invariant)
  short8 phB[4][2];
  #pragma unroll
  for (int nt = 0; nt < 4; ++nt){
    const short* pp = phi_s + (size_t)(n0 + nt*16 + l15)*ICH + quad*8;
    phB[nt][0] = *reinterpret_cast<const short8*>(pp);
    phB[nt][1] = *reinterpret_cast<const short8*>(pp + 32);
  }

  // x-direction Gaussian factors (computed, loop-invariant)
  float wxv[4][4];
  {
    const int xm = w*16 + quad*4;
    #pragma unroll
    for (int nt = 0; nt < 4; ++nt){
      int xn = nt*16 + l15;
      #pragma unroll
      for (int r = 0; r < 4; ++r){
        int dx = xn - (xm + r);
        wxv[nt][r] = exp2f(coefL * (float)(dx*dx));
      }
    }
  }

  const int ci = w >> 1, nj = w & 1;
  floatx4 oacc[2][2];
  #pragma unroll
  for (int a = 0; a < 2; ++a)
    #pragma unroll
    for (int b = 0; b < 2; ++b) oacc[a][b] = (floatx4){0.f,0.f,0.f,0.f};
  float psum[4] = {0.f,0.f,0.f,0.f};

  int m0 = sp*MCHUNK;
  for (int it = 0; it < MCHUNK/64; ++it, m0 += 64){
    const int buf = it & 1;

    // prefetch g A-frags (consumed after barrier)
    short8 gA[2][2];
    #pragma unroll
    for (int ct = 0; ct < 2; ++ct){
      const short* gp = g_s + (size_t)(ci*32 + ct*16 + l15)*NHW + m0 + quad*8;
      gA[ct][0] = *reinterpret_cast<const short8*>(gp);
      gA[ct][1] = *reinterpret_cast<const short8*>(gp + 32);
    }

    // theta A-frag (wave-unique 16 m)
    const short* tp = th_s + (size_t)(m0 + w*16 + l15)*ICH + quad*8;
    short8 a0 = *reinterpret_cast<const short8*>(tp);
    short8 a1 = *reinterpret_cast<const short8*>(tp + 32);

    // S^T[m-tile w][all n]  (already xLOG2E)
    floatx4 s[4];
    #pragma unroll
    for (int nt = 0; nt < 4; ++nt){
      floatx4 acc = (floatx4){0.f,0.f,0.f,0.f};
      acc = __builtin_amdgcn_mfma_f32_16x16x32_bf16(a0, phB[nt][0], acc, 0, 0, 0);
      s[nt] = __builtin_amdgcn_mfma_f32_16x16x32_bf16(a1, phB[nt][1], acc, 0, 0, 0);
    }

    // exp2 + weight + P write (packed bf16 cvt)
    const int ym = m0 >> 6;
    const int dy = yn - ym;
    const float wyv = exp2f(coefL * (float)(dy*dy));
    #pragma unroll
    for (int nt = 0; nt < 4; ++nt){
      float pw[4];
      #pragma unroll
      for (int r = 0; r < 4; ++r){
        float p = exp2f(s[nt][r]);
        psum[nt] += p;
        pw[r] = p * (wyv * wxv[nt][r]);
      }
      __hip_bfloat162 lo = __float22bfloat162_rn(make_float2(pw[0], pw[1]));
      __hip_bfloat162 hi = __float22bfloat162_rn(make_float2(pw[2], pw[3]));
      uint2 u;
      u.x = *reinterpret_cast<unsigned*>(&lo);
      u.y = *reinterpret_cast<unsigned*>(&hi);
      *reinterpret_cast<uint2*>(&Plds[buf][nt*16 + l15][w*16 + quad*4]) = u;
    }

    __syncthreads();

    // P B-frags (own n-half)
    short8 pB[2][2];
    #pragma unroll
    for (int nt2 = 0; nt2 < 2; ++nt2){
      const short* pr = &Plds[buf][nj*32 + nt2*16 + l15][quad*8];
      pB[nt2][0] = *reinterpret_cast<const short8*>(pr);
      pB[nt2][1] = *reinterpret_cast<const short8*>(pr + 32);
    }

    // O += g @ P
    #pragma unroll
    for (int ct = 0; ct < 2; ++ct)
      #pragma unroll
      for (int nt2 = 0; nt2 < 2; ++nt2){
        oacc[ct][nt2] = __builtin_amdgcn_mfma_f32_16x16x32_bf16(gA[ct][0], pB[nt2][0], oacc[ct][nt2], 0, 0, 0);
        oacc[ct][nt2] = __builtin_amdgcn_mfma_f32_16x16x32_bf16(gA[ct][1], pB[nt2][1], oacc[ct][nt2], 0, 0, 0);
      }
  }

  // epilogue: Opart [c][n] — 16 consecutive lanes = one full 64B line
  float* Ob = Opart + (size_t)(t*NSPLIT + sp)*ICH*NHW;
  #pragma unroll
  for (int ct = 0; ct < 2; ++ct)
    #pragma unroll
    for (int nt2 = 0; nt2 < 2; ++nt2){
      int c = ci*32 + ct*16 + quad*4;
      int n = n0 + nj*32 + nt2*16 + l15;
      #pragma unroll
      for (int r = 0; r < 4; ++r)
        Ob[(size_t)(c + r)*NHW + n] = oacc[ct][nt2][r];
    }

  // Z reduce
  #pragma unroll
  for (int nt = 0; nt < 4; ++nt){
    float z = psum[nt];
    z += __shfl_xor(z, 16);
    z += __shfl_xor(z, 32);
    psum[nt] = z;
  }
  if (quad == 0){
    #pragma unroll
    for (int nt = 0; nt < 4; ++nt) Zsh[w][nt*16 + l15] = psum[nt];
  }
  __syncthreads();
  if (threadIdx.x < 64){
    float z = Zsh[0][threadIdx.x] + Zsh[1][threadIdx.x] + Zsh[2][threadIdx.x] + Zsh[3][threadIdx.x];
    Zpart[(size_t)(t*NSPLIT + sp)*NHW + n0 + threadIdx.x] = z;
  }
}

// ---------------- fused post: blocks 0..447 merge partials -> corrT[n][0..447];
// blocks 448..575 memory-bank path -> corrT[n][448..511] + qpart
__global__ __launch_bounds__(256) void k_post(const float* __restrict__ Opart,
    const float* __restrict__ Zpart,
    const __hip_bfloat16* __restrict__ phi_bf,
    const __hip_bfloat16* __restrict__ mbT, const __hip_bfloat16* __restrict__ mbbf,
    __hip_bfloat16* __restrict__ corrT, float* __restrict__ qpart){
  __shared__ short tile[64][72];
  __shared__ float zinv[64];
  __shared__ short P[32][264];
  __shared__ float Zsh[4][32];
  __shared__ float qred[4];

  const int b = blockIdx.x;
  if (b < 448){
    const int t = b >> 6, n0 = (b & 63)*64;
    if (threadIdx.x < 64){
      float zs = 0.f;
      #pragma unroll
      for (int s = 0; s < NSPLIT; ++s)
        zs += Zpart[(size_t)(t*NSPLIT + s)*NHW + n0 + threadIdx.x];
      zinv[threadIdx.x] = 1.f / zs;
    }
    __syncthreads();

    const int nq = threadIdx.x & 15, cc = threadIdx.x >> 4;
    #pragma unroll
    for (int cp = 0; cp < 4; ++cp){
      int c = cp*16 + cc;
      float4 acc = {0.f,0.f,0.f,0.f};
      #pragma unroll
      for (int s = 0; s < NSPLIT; ++s){
        float4 v = *reinterpret_cast<const float4*>(
          Opart + ((size_t)(t*NSPLIT + s)*ICH + c)*NHW + n0 + nq*4);
        acc.x += v.x; acc.y += v.y; acc.z += v.z; acc.w += v.w;
      }
      tile[nq*4+0][c] = f2bf(acc.x * zinv[nq*4+0]);
      tile[nq*4+1][c] = f2bf(acc.y * zinv[nq*4+1]);
      tile[nq*4+2][c] = f2bf(acc.z * zinv[nq*4+2]);
      tile[nq*4+3][c] = f2bf(acc.w * zinv[nq*4+3]);
    }
    __syncthreads();

    #pragma unroll
    for (int rep = 0; rep < 2; ++rep){
      int idx = rep*256 + threadIdx.x;
      int n = idx >> 3, seg = idx & 7;
      short8 v = *reinterpret_cast<short8*>(&tile[n][seg*8]);
      *reinterpret_cast<short8*>(reinterpret_cast<short*>(corrT)
          + (size_t)(n0 + n)*512 + t*64 + seg*8) = v;
    }
  } else {
    const int mbid = b - 448;
    const int n0 = mbid*32;
    const int w = threadIdx.x >> 6, lane = threadIdx.x & 63;
    const int l15 = lane & 15, quad = lane >> 4;

    const short* phi_s = reinterpret_cast<const short*>(phi_bf);
    const short* mbT_s = reinterpret_cast<const short*>(mbT);
    const short* mb_s  = reinterpret_cast<const short*>(mbbf);

    short8 Bp[2][2];
    #pragma unroll
    for (int nt = 0; nt < 2; ++nt){
      const short* pp = phi_s + (size_t)(n0 + nt*16 + l15)*ICH + quad*8;
      Bp[nt][0] = *reinterpret_cast<const short8*>(pp);
      Bp[nt][1] = *reinterpret_cast<const short8*>(pp + 32);
    }
    float psum[2] = {0.f, 0.f};
    #pragma unroll
    for (int jt = 0; jt < 4; ++jt){
      const short* ap = mbT_s + (size_t)(w*64 + jt*16 + l15)*64 + quad*8;
      short8 A0 = *reinterpret_cast<const short8*>(ap);
      short8 A1 = *reinterpret_cast<const short8*>(ap + 32);
      #pragma unroll
      for (int nt = 0; nt < 2; ++nt){
        floatx4 acc = (floatx4){0.f,0.f,0.f,0.f};
        acc = __builtin_amdgcn_mfma_f32_16x16x32_bf16(A0, Bp[nt][0], acc, 0, 0, 0);
        acc = __builtin_amdgcn_mfma_f32_16x16x32_bf16(A1, Bp[nt][1], acc, 0, 0, 0);
        sshort4 pk;
        #pragma unroll
        for (int r = 0; r < 4; ++r){
          float p = exp2f(acc[r] * (0.125f*LOG2E));
          psum[nt] += p;
          pk[r] = f2bf(p);
        }
        *reinterpret_cast<sshort4*>(&P[nt*16 + l15][w*64 + jt*16 + quad*4]) = pk;
      }
    }
    #pragma unroll
    for (int nt = 0; nt < 2; ++nt){
      float z = psum[nt];
      z += __shfl_xor(z, 16);
      z += __shfl_xor(z, 32);
      if (quad == 0) Zsh[w][nt*16 + l15] = z;
    }
    __syncthreads();

    float ql = 0.f;
    #pragma unroll
    for (int nt = 0; nt < 2; ++nt){
      floatx4 acc = (floatx4){0.f,0.f,0.f,0.f};
      #pragma unroll
      for (int kk = 0; kk < 8; ++kk){
        const short* ap = mb_s + (size_t)(w*16 + l15)*256 + kk*32 + quad*8;
        short8 A = *reinterpret_cast<const short8*>(ap);
        short8 Bv = *reinterpret_cast<const short8*>(&P[nt*16 + l15][kk*32 + quad*8]);
        acc = __builtin_amdgcn_mfma_f32_16x16x32_bf16(A, Bv, acc, 0, 0, 0);
      }
      int nn = nt*16 + l15;
      float zt = Zsh[0][nn] + Zsh[1][nn] + Zsh[2][nn] + Zsh[3][nn];
      float rz = 1.f / zt;
      const short* ph = phi_s + (size_t)(n0 + nn)*ICH + w*16 + quad*4;
      sshort4 ph4 = *reinterpret_cast<const sshort4*>(ph);
      sshort4 pk;
      #pragma unroll
      for (int r = 0; r < 4; ++r){
        float y = acc[r] * rz;
        ql += fabsf(bf2f(ph4[r]) - y);
        pk[r] = f2bf(y);
      }
      short* dst = reinterpret_cast<short*>(corrT) + (size_t)(n0 + nn)*512 + 448 + w*16 + quad*4;
      *reinterpret_cast<sshort4*>(dst) = pk;
    }
    #pragma unroll
    for (int off = 32; off; off >>= 1) ql += __shfl_xor(ql, off);
    if (lane == 0) qred[w] = ql;
    __syncthreads();
    if (threadIdx.x == 0)
      qpart[mbid] = qred[0] + qred[1] + qred[2] + qred[3];
  }
}

// ---------------- z via MFMA: out[o][n] = wzcat @ corrT^T + biasz + q; qloss write
__global__ __launch_bounds__(256) void k_z(const __hip_bfloat16* __restrict__ corrT,
    const __hip_bfloat16* __restrict__ wzcat, const float* __restrict__ biasz,
    const float* __restrict__ x, const float* __restrict__ qpart,
    float* __restrict__ out){
  const int n0 = blockIdx.x*16;
  const int w = threadIdx.x >> 6, lane = threadIdx.x & 63;
  const int l15 = lane & 15, quad = lane >> 4;
  const int o0 = blockIdx.y*64 + w*16;

  const short* ct_s = reinterpret_cast<const short*>(corrT) + (size_t)(n0 + l15)*512 + quad*8;
  const short* wz_s = reinterpret_cast<const short*>(wzcat) + (size_t)(o0 + l15)*512 + quad*8;

  floatx4 acc = (floatx4){0.f,0.f,0.f,0.f};
  #pragma unroll
  for (int kk = 0; kk < 16; ++kk){
    short8 A = *reinterpret_cast<const short8*>(wz_s + kk*32);
    short8 B = *reinterpret_cast<const short8*>(ct_s + kk*32);
    acc = __builtin_amdgcn_mfma_f32_16x16x32_bf16(A, B, acc, 0, 0, 0);
  }
  float4 bz = *reinterpret_cast<const float4*>(biasz + o0 + quad*4);
  float bzv[4] = {bz.x, bz.y, bz.z, bz.w};
  #pragma unroll
  for (int r = 0; r < 4; ++r){
    int o = o0 + quad*4 + r;
    int n = n0 + l15;
    float q = x[((size_t)3*CCH + o)*NHW + n];
    out[(size_t)o*NHW + n] = acc[r] + bzv[r] + q;
  }
  if (blockIdx.x == 0 && blockIdx.y == 0 && threadIdx.x == 0){
    float s = 0.f;
    for (int i = 0; i < 128; ++i) s += qpart[i];
    out[(size_t)CCH*NHW] = s * (1.f/262144.f);
  }
}

extern "C" void kernel_launch(void* const* d_in, const int* in_sizes, int n_in,
                              void* d_out, int out_size, void* d_ws, size_t ws_size,
                              hipStream_t stream){
  const float* x     = (const float*)d_in[0];
  const float* gamma = (const float*)d_in[1];
  const float* beta  = (const float*)d_in[2];
  const float* g_w   = (const float*)d_in[3];
  const float* g_b   = (const float*)d_in[4];
  const float* th_w  = (const float*)d_in[5];
  const float* th_b  = (const float*)d_in[6];
  const float* ph_w  = (const float*)d_in[7];
  const float* ph_b  = (const float*)d_in[8];
  const float* wz_w  = (const float*)d_in[9];
  const float* wz_b  = (const float*)d_in[10];
  const float* wz1_w = (const float*)d_in[11];
  const float* wz1_b = (const float*)d_in[12];
  const float* mb    = (const float*)d_in[13];
  const float* stdp  = (const float*)d_in[14];
  float* out = (float*)d_out;

  char* ws = (char*)d_ws;
  size_t off = 0;
  auto alloc = [&](size_t bytes)->char*{
    char* p = ws + off; off += (bytes + 255) & ~(size_t)255; return p;
  };
  float* spart   = (float*)alloc((size_t)64*224*4);
  float* spart2  = (float*)alloc((size_t)64*224*4);
  float* qpart   = (float*)alloc(128*4);
  __hip_bfloat16* xbf    = (__hip_bfloat16*)alloc((size_t)TT*NHW*CCH*2);
  __hip_bfloat16* Wth    = (__hip_bfloat16*)alloc((size_t)TT*ICH*CCH*2);
  float* bth             = (float*)alloc(TT*64*4);
  __hip_bfloat16* Wg     = (__hip_bfloat16*)alloc((size_t)TT*ICH*CCH*2);
  float* bg              = (float*)alloc(TT*64*4);
  __hip_bfloat16* Wphi   = (__hip_bfloat16*)alloc((size_t)ICH*CCH*2);
  float* bphi            = (float*)alloc(64*4);
  __hip_bfloat16* wzcat  = (__hip_bfloat16*)alloc((size_t)128*512*2);
  float* biasz           = (float*)alloc(128*4);
  __hip_bfloat16* mbT    = (__hip_bfloat16*)alloc((size_t)256*64*2);
  __hip_bfloat16* mbbf   = (__hip_bfloat16*)alloc((size_t)64*256*2);
  __hip_bfloat16* thetaT = (__hip_bfloat16*)alloc((size_t)TT*NHW*ICH*2);
  __hip_bfloat16* g_nat  = (__hip_bfloat16*)alloc((size_t)TT*NHW*ICH*2);
  __hip_bfloat16* phi_bf = (__hip_bfloat16*)alloc((size_t)NHW*ICH*2);
  __hip_bfloat16* corrT  = (__hip_bfloat16*)alloc((size_t)NHW*512*2);
  float* Opart   = (float*)alloc((size_t)TT*NSPLIT*ICH*NHW*4);
  float* Zpart   = (float*)alloc((size_t)TT*NSPLIT*NHW*4);

  k_precast<<<dim3(64,7,2), 256, 0, stream>>>(x, xbf, spart, spart2);
  k_setup<<<368, 256, 0, stream>>>(g_w, g_b, th_w, th_b, ph_w, ph_b, gamma, beta,
                                   spart, spart2, Wth, bth, Wg, bg, Wphi, bphi,
                                   wz_w, wz1_w, wz_b, wz1_b, mb, wzcat, biasz, mbT, mbbf);
  k_conv<<<dim3(64,7,2), 256, 0, stream>>>(xbf, Wth, bth, Wg, bg, Wphi, bphi,
                                           thetaT, g_nat, phi_bf);
  k_attn<<<dim3(64,NSPLIT,7), 256, 0, stream>>>(phi_bf, thetaT, g_nat, stdp, Opart, Zpart);
  k_post<<<576, 256, 0, stream>>>(Opart, Zpart, phi_bf, mbT, mbbf, corrT, qpart);
  k_z   <<<dim3(256,2), 256, 0, stream>>>(corrT, wzcat, biasz, x, qpart, out);
}

// Round 12
// 215.884 us; speedup vs baseline: 1.2391x; 1.2391x over previous
//
#include <hip/hip_runtime.h>
#include <hip/hip_bf16.h>

#define TT 7
#define CCH 128
#define ICH 64
#define NHW 4096
#define NSPLIT 4
#define MCHUNK (NHW/NSPLIT)

typedef __attribute__((ext_vector_type(8))) short short8;
typedef __attribute__((ext_vector_type(4))) short sshort4;
typedef __attribute__((ext_vector_type(4))) float floatx4;

#define LOG2E 1.44269504f

static __device__ __forceinline__ short f2bf(float f){
  __hip_bfloat16 h = __float2bfloat16(f);
  return *reinterpret_cast<short*>(&h);
}
static __device__ __forceinline__ float bf2f(short s){
  __hip_bfloat16 h = *reinterpret_cast<__hip_bfloat16*>(&s);
  return __bfloat162float(h);
}

// ---------------- fused cast+stats: xbf[t][n][c] bf16; per-block stat partials
// spart/spart2 layout: [nx][224] (group = t*32 + zh*16 + w*4 + g) — no memset needed.
__global__ __launch_bounds__(256) void k_precast(const float* __restrict__ x,
    __hip_bfloat16* __restrict__ xbf, float* __restrict__ spart, float* __restrict__ spart2){
  __shared__ short tile[64][66];
  int t = blockIdx.y, n0 = blockIdx.x*64, zh = blockIdx.z;
  int ln = threadIdx.x & 63, w = threadIdx.x >> 6;
  float sl[4] = {0.f,0.f,0.f,0.f}, s2l[4] = {0.f,0.f,0.f,0.f};
  #pragma unroll 4
  for (int ci = 0; ci < 16; ++ci){
    int cl = w*16 + ci;
    float v = x[((size_t)t*CCH + zh*64 + cl)*NHW + n0 + ln];
    tile[ln][cl] = f2bf(v);
    sl[ci>>2]  += v;
    s2l[ci>>2] += v*v;
  }
  #pragma unroll
  for (int off = 32; off; off >>= 1){
    #pragma unroll
    for (int g = 0; g < 4; ++g){
      sl[g]  += __shfl_xor(sl[g],  off);
      s2l[g] += __shfl_xor(s2l[g], off);
    }
  }
  if (ln == 0){
    float* sp  = spart  + (size_t)blockIdx.x*224 + t*32 + zh*16 + w*4;
    float* sp2 = spart2 + (size_t)blockIdx.x*224 + t*32 + zh*16 + w*4;
    #pragma unroll
    for (int g = 0; g < 4; ++g){ sp[g] = sl[g]; sp2[g] = s2l[g]; }
  }
  __syncthreads();
  int row = threadIdx.x >> 2, seg = threadIdx.x & 3;
  short* dst = reinterpret_cast<short*>(xbf) + ((size_t)t*NHW + n0 + row)*CCH + zh*64 + seg*16;
  #pragma unroll
  for (int k = 0; k < 2; ++k){
    short8 v;
    #pragma unroll
    for (int j = 0; j < 8; ++j) v[j] = tile[row][seg*16 + k*8 + j];
    *reinterpret_cast<short8*>(dst + k*8) = v;
  }
}

// ---------------- setup: GN-fold (theta scaled by LOG2E) + wz/mb prep
__global__ __launch_bounds__(256) void k_setup(
    const float* __restrict__ gw, const float* __restrict__ gb,
    const float* __restrict__ thw, const float* __restrict__ thb,
    const float* __restrict__ phw, const float* __restrict__ phb,
    const float* __restrict__ gamma, const float* __restrict__ beta,
    const float* __restrict__ spart, const float* __restrict__ spart2,
    __hip_bfloat16* __restrict__ Wth, float* __restrict__ bth,
    __hip_bfloat16* __restrict__ Wg,  float* __restrict__ bg,
    __hip_bfloat16* __restrict__ Wphi, float* __restrict__ bphi,
    const float* __restrict__ wz, const float* __restrict__ wz1,
    const float* __restrict__ wz_b, const float* __restrict__ wz1_b,
    const float* __restrict__ mb,
    __hip_bfloat16* __restrict__ wzcat, float* __restrict__ biasz,
    __hip_bfloat16* __restrict__ mbT, __hip_bfloat16* __restrict__ mbbf){
  if (blockIdx.x < 240){
    int w = threadIdx.x >> 6, lane = threadIdx.x & 63;
    int oidx = blockIdx.x*4 + w;
    const float *W, *B; __hip_bfloat16 *Wf; float *bfo; int t, o;
    float scale = 1.f;
    if (oidx < 448){ t = oidx >> 6; o = oidx & 63; W = thw; B = thb; Wf = Wth + ((size_t)t*ICH + o)*CCH; bfo = bth + t*64 + o; scale = LOG2E; }
    else if (oidx < 896){ int j = oidx - 448; t = j >> 6; o = j & 63; W = gw; B = gb; Wf = Wg + ((size_t)t*ICH + o)*CCH; bfo = bg + t*64 + o; }
    else { t = 3; o = oidx - 896; W = phw; B = phb; Wf = Wphi + (size_t)o*CCH; bfo = bphi + o; }
    // per-lane group stats (sum 64 per-block partials; mostly broadcast loads)
    float mv[2], rv[2];
    #pragma unroll
    for (int h = 0; h < 2; ++h){
      int gid = t*32 + ((h*64 + lane) >> 2);
      float S = 0.f, S2 = 0.f;
      for (int i = 0; i < 64; ++i){
        S  += spart [(size_t)i*224 + gid];
        S2 += spart2[(size_t)i*224 + gid];
      }
      float m  = S * (1.f/16384.f);
      float vr = S2 * (1.f/16384.f) - m*m;
      mv[h] = m;
      rv[h] = rsqrtf(vr + 1e-6f);
    }
    float bp = 0.f;
    #pragma unroll
    for (int h = 0; h < 2; ++h){
      int c = h*64 + lane;
      float a  = gamma[c]*rv[h];
      float wv = W[o*CCH + c];
      Wf[c] = __float2bfloat16(wv * a * scale);
      bp += wv * (beta[c] - mv[h]*a);
    }
    #pragma unroll
    for (int off = 32; off; off >>= 1) bp += __shfl_xor(bp, off);
    if (lane == 0) *bfo = (bp + B[o]) * scale;
  } else {
    int idx = (blockIdx.x - 240)*256 + threadIdx.x;   // 0..32767
    #pragma unroll
    for (int k = 0; k < 2; ++k){
      int i = idx + k*32768;
      int o = i >> 9, kk = i & 511;
      float v = (kk < 448) ? wz[o*448 + kk] : wz1[o*64 + (kk-448)];
      wzcat[i] = __float2bfloat16(v);
    }
    if (idx < 128) biasz[idx] = wz_b[idx] + wz1_b[idx];
    if (idx < 64*256){
      int c = idx >> 8, j = idx & 255;
      float v = mb[idx];
      mbbf[idx] = __float2bfloat16(v);
      mbT[j*64 + c] = __float2bfloat16(v);
    }
  }
}

// ---------------- conv1x1 via MFMA, split z: 0 = theta(+phi), 1 = g
__global__ __launch_bounds__(256) void k_conv(const __hip_bfloat16* __restrict__ xbf,
    const __hip_bfloat16* __restrict__ Wth, const float* __restrict__ bth,
    const __hip_bfloat16* __restrict__ Wg,  const float* __restrict__ bg,
    const __hip_bfloat16* __restrict__ Wphi, const float* __restrict__ bphi,
    __hip_bfloat16* __restrict__ thetaT, __hip_bfloat16* __restrict__ g_nat,
    __hip_bfloat16* __restrict__ phi_bf){
  const int t = blockIdx.y, n0 = blockIdx.x*64, job = blockIdx.z;
  const int w = threadIdx.x >> 6, lane = threadIdx.x & 63;
  const int l15 = lane & 15, quad = lane >> 4;

  const short* xb = reinterpret_cast<const short*>(xbf) + ((size_t)t*NHW + n0)*CCH;
  short8 B[4][4];
  #pragma unroll
  for (int nt = 0; nt < 4; ++nt)
    #pragma unroll
    for (int kk = 0; kk < 4; ++kk)
      B[nt][kk] = *reinterpret_cast<const short8*>(xb + (size_t)(nt*16 + l15)*CCH + kk*32 + quad*8);

  if (job == 0){
    { // theta
      const short* aw = reinterpret_cast<const short*>(Wth) + ((size_t)t*ICH + w*16 + l15)*CCH + quad*8;
      short8 A[4];
      #pragma unroll
      for (int kk = 0; kk < 4; ++kk) A[kk] = *reinterpret_cast<const short8*>(aw + kk*32);
      float4 bv = *reinterpret_cast<const float4*>(bth + t*64 + w*16 + quad*4);
      #pragma unroll
      for (int nt = 0; nt < 4; ++nt){
        floatx4 acc = (floatx4){0.f,0.f,0.f,0.f};
        #pragma unroll
        for (int kk = 0; kk < 4; ++kk) acc = __builtin_amdgcn_mfma_f32_16x16x32_bf16(A[kk], B[nt][kk], acc, 0, 0, 0);
        sshort4 pk;
        pk[0] = f2bf(acc[0] + bv.x); pk[1] = f2bf(acc[1] + bv.y);
        pk[2] = f2bf(acc[2] + bv.z); pk[3] = f2bf(acc[3] + bv.w);
        short* dst = reinterpret_cast<short*>(thetaT) + ((size_t)t*NHW + n0 + nt*16 + l15)*ICH + w*16 + quad*4;
        *reinterpret_cast<sshort4*>(dst) = pk;
      }
    }
    if (t == 3){ // phi
      const short* aw = reinterpret_cast<const short*>(Wphi) + (size_t)(w*16 + l15)*CCH + quad*8;
      short8 A[4];
      #pragma unroll
      for (int kk = 0; kk < 4; ++kk) A[kk] = *reinterpret_cast<const short8*>(aw + kk*32);
      float4 bv = *reinterpret_cast<const float4*>(bphi + w*16 + quad*4);
      #pragma unroll
      for (int nt = 0; nt < 4; ++nt){
        floatx4 acc = (floatx4){0.f,0.f,0.f,0.f};
        #pragma unroll
        for (int kk = 0; kk < 4; ++kk) acc = __builtin_amdgcn_mfma_f32_16x16x32_bf16(A[kk], B[nt][kk], acc, 0, 0, 0);
        sshort4 pk;
        pk[0] = f2bf(acc[0] + bv.x); pk[1] = f2bf(acc[1] + bv.y);
        pk[2] = f2bf(acc[2] + bv.z); pk[3] = f2bf(acc[3] + bv.w);
        short* dst = reinterpret_cast<short*>(phi_bf) + (size_t)(n0 + nt*16 + l15)*ICH + w*16 + quad*4;
        *reinterpret_cast<sshort4*>(dst) = pk;
      }
    }
  } else { // g
    const short* aw = reinterpret_cast<const short*>(Wg) + ((size_t)t*ICH + w*16 + l15)*CCH + quad*8;
    short8 A[4];
    #pragma unroll
    for (int kk = 0; kk < 4; ++kk) A[kk] = *reinterpret_cast<const short8*>(aw + kk*32);
    float4 bv = *reinterpret_cast<const float4*>(bg + t*64 + w*16 + quad*4);
    #pragma unroll
    for (int nt = 0; nt < 4; ++nt){
      floatx4 acc = (floatx4){0.f,0.f,0.f,0.f};
      #pragma unroll
      for (int kk = 0; kk < 4; ++kk) acc = __builtin_amdgcn_mfma_f32_16x16x32_bf16(A[kk], B[nt][kk], acc, 0, 0, 0);
      short* gb = reinterpret_cast<short*>(g_nat);
      float bvv[4] = {bv.x, bv.y, bv.z, bv.w};
      #pragma unroll
      for (int r = 0; r < 4; ++r)
        gb[((size_t)t*ICH + w*16 + quad*4 + r)*NHW + n0 + nt*16 + l15] = f2bf(acc[r] + bvv[r]);
    }
  }
}

// ---------------- split-K flash attention (theta pre-scaled so p=exp2(s))
// Opart[(t,sp)][c][n] fp32 full-line stores; Zpart[(t,sp)][n]
// NOTE on launch bounds: total (VGPR+AGPR) live set is in (102, 128]. Bound 4
// (budget 128) is the ONLY safe point: bound 5 (102) mild-spills (R11: FETCH 39MB,
// WRITE 52MB, 151us), bound 6 (85) and 8 (64) spill catastrophically (R9: 395MB
// FETCH; R5: 1.9GB). DO NOT raise past 4.
__global__ __launch_bounds__(256, 4) void k_attn(
    const __hip_bfloat16* __restrict__ phi_bf,   // [n][64]
    const __hip_bfloat16* __restrict__ thetaT,   // [t][m][64] (xLOG2E)
    const __hip_bfloat16* __restrict__ g_nat,    // [t][c][m]
    const float* __restrict__ stdp,
    float* __restrict__ Opart, float* __restrict__ Zpart)
{
  const int t    = blockIdx.z;
  const int sp   = blockIdx.y;
  const int w    = threadIdx.x >> 6;
  const int lane = threadIdx.x & 63;
  const int l15  = lane & 15;
  const int quad = lane >> 4;
  const int n0   = blockIdx.x*64;
  const int yn   = blockIdx.x;

  __shared__ short Plds[2][64][72];   // [buf][n][m + pad]
  __shared__ float Zsh[4][64];

  const float sstd  = stdp[0];
  const float coefL = -0.5f / (sstd*sstd) * LOG2E;

  const short* phi_s = reinterpret_cast<const short*>(phi_bf);
  const short* th_s  = reinterpret_cast<const short*>(thetaT) + (size_t)t*NHW*ICH;
  const short* g_s   = reinterpret_cast<const short*>(g_nat)  + (size_t)t*ICH*NHW;

  // phi B-frags for ALL 64 n (loop-invariant)
  short8 phB[4][2];
  #pragma unroll
  for (int nt = 0; nt < 4; ++nt){
    const short* pp = phi_s + (size_t)(n0 + nt*16 + l15)*ICH + quad*8;
    phB[nt][0] = *reinterpret_cast<const short8*>(pp);
    phB[nt][1] = *reinterpret_cast<const short8*>(pp + 32);
  }

  // x-direction Gaussian factors (computed, loop-invariant)
  float wxv[4][4];
  {
    const int xm = w*16 + quad*4;
    #pragma unroll
    for (int nt = 0; nt < 4; ++nt){
      int xn = nt*16 + l15;
      #pragma unroll
      for (int r = 0; r < 4; ++r){
        int dx = xn - (xm + r);
        wxv[nt][r] = exp2f(coefL * (float)(dx*dx));
      }
    }
  }

  const int ci = w >> 1, nj = w & 1;
  floatx4 oacc[2][2];
  #pragma unroll
  for (int a = 0; a < 2; ++a)
    #pragma unroll
    for (int b = 0; b < 2; ++b) oacc[a][b] = (floatx4){0.f,0.f,0.f,0.f};
  float psum[4] = {0.f,0.f,0.f,0.f};

  int m0 = sp*MCHUNK;
  for (int it = 0; it < MCHUNK/64; ++it, m0 += 64){
    const int buf = it & 1;

    // prefetch g A-frags (consumed after barrier)
    short8 gA[2][2];
    #pragma unroll
    for (int ct = 0; ct < 2; ++ct){
      const short* gp = g_s + (size_t)(ci*32 + ct*16 + l15)*NHW + m0 + quad*8;
      gA[ct][0] = *reinterpret_cast<const short8*>(gp);
      gA[ct][1] = *reinterpret_cast<const short8*>(gp + 32);
    }

    // theta A-frag (wave-unique 16 m)
    const short* tp = th_s + (size_t)(m0 + w*16 + l15)*ICH + quad*8;
    short8 a0 = *reinterpret_cast<const short8*>(tp);
    short8 a1 = *reinterpret_cast<const short8*>(tp + 32);

    // S^T[m-tile w][all n]  (already xLOG2E)
    floatx4 s[4];
    #pragma unroll
    for (int nt = 0; nt < 4; ++nt){
      floatx4 acc = (floatx4){0.f,0.f,0.f,0.f};
      acc = __builtin_amdgcn_mfma_f32_16x16x32_bf16(a0, phB[nt][0], acc, 0, 0, 0);
      s[nt] = __builtin_amdgcn_mfma_f32_16x16x32_bf16(a1, phB[nt][1], acc, 0, 0, 0);
    }

    // exp2 + weight + P write (packed bf16 cvt)
    const int ym = m0 >> 6;
    const int dy = yn - ym;
    const float wyv = exp2f(coefL * (float)(dy*dy));
    #pragma unroll
    for (int nt = 0; nt < 4; ++nt){
      float pw[4];
      #pragma unroll
      for (int r = 0; r < 4; ++r){
        float p = exp2f(s[nt][r]);
        psum[nt] += p;
        pw[r] = p * (wyv * wxv[nt][r]);
      }
      __hip_bfloat162 lo = __float22bfloat162_rn(make_float2(pw[0], pw[1]));
      __hip_bfloat162 hi = __float22bfloat162_rn(make_float2(pw[2], pw[3]));
      uint2 u;
      u.x = *reinterpret_cast<unsigned*>(&lo);
      u.y = *reinterpret_cast<unsigned*>(&hi);
      *reinterpret_cast<uint2*>(&Plds[buf][nt*16 + l15][w*16 + quad*4]) = u;
    }

    __syncthreads();

    // P B-frags (own n-half)
    short8 pB[2][2];
    #pragma unroll
    for (int nt2 = 0; nt2 < 2; ++nt2){
      const short* pr = &Plds[buf][nj*32 + nt2*16 + l15][quad*8];
      pB[nt2][0] = *reinterpret_cast<const short8*>(pr);
      pB[nt2][1] = *reinterpret_cast<const short8*>(pr + 32);
    }

    // O += g @ P
    #pragma unroll
    for (int ct = 0; ct < 2; ++ct)
      #pragma unroll
      for (int nt2 = 0; nt2 < 2; ++nt2){
        oacc[ct][nt2] = __builtin_amdgcn_mfma_f32_16x16x32_bf16(gA[ct][0], pB[nt2][0], oacc[ct][nt2], 0, 0, 0);
        oacc[ct][nt2] = __builtin_amdgcn_mfma_f32_16x16x32_bf16(gA[ct][1], pB[nt2][1], oacc[ct][nt2], 0, 0, 0);
      }
  }

  // epilogue: Opart [c][n] — 16 consecutive lanes = one full 64B line
  float* Ob = Opart + (size_t)(t*NSPLIT + sp)*ICH*NHW;
  #pragma unroll
  for (int ct = 0; ct < 2; ++ct)
    #pragma unroll
    for (int nt2 = 0; nt2 < 2; ++nt2){
      int c = ci*32 + ct*16 + quad*4;
      int n = n0 + nj*32 + nt2*16 + l15;
      #pragma unroll
      for (int r = 0; r < 4; ++r)
        Ob[(size_t)(c + r)*NHW + n] = oacc[ct][nt2][r];
    }

  // Z reduce
  #pragma unroll
  for (int nt = 0; nt < 4; ++nt){
    float z = psum[nt];
    z += __shfl_xor(z, 16);
    z += __shfl_xor(z, 32);
    psum[nt] = z;
  }
  if (quad == 0){
    #pragma unroll
    for (int nt = 0; nt < 4; ++nt) Zsh[w][nt*16 + l15] = psum[nt];
  }
  __syncthreads();
  if (threadIdx.x < 64){
    float z = Zsh[0][threadIdx.x] + Zsh[1][threadIdx.x] + Zsh[2][threadIdx.x] + Zsh[3][threadIdx.x];
    Zpart[(size_t)(t*NSPLIT + sp)*NHW + n0 + threadIdx.x] = z;
  }
}

// ---------------- fused post: blocks 0..447 merge partials -> corrT[n][0..447];
// blocks 448..575 memory-bank path -> corrT[n][448..511] + qpart
__global__ __launch_bounds__(256) void k_post(const float* __restrict__ Opart,
    const float* __restrict__ Zpart,
    const __hip_bfloat16* __restrict__ phi_bf,
    const __hip_bfloat16* __restrict__ mbT, const __hip_bfloat16* __restrict__ mbbf,
    __hip_bfloat16* __restrict__ corrT, float* __restrict__ qpart){
  __shared__ short tile[64][72];
  __shared__ float zinv[64];
  __shared__ short P[32][264];
  __shared__ float Zsh[4][32];
  __shared__ float qred[4];

  const int b = blockIdx.x;
  if (b < 448){
    const int t = b >> 6, n0 = (b & 63)*64;
    if (threadIdx.x < 64){
      float zs = 0.f;
      #pragma unroll
      for (int s = 0; s < NSPLIT; ++s)
        zs += Zpart[(size_t)(t*NSPLIT + s)*NHW + n0 + threadIdx.x];
      zinv[threadIdx.x] = 1.f / zs;
    }
    __syncthreads();

    const int nq = threadIdx.x & 15, cc = threadIdx.x >> 4;
    #pragma unroll
    for (int cp = 0; cp < 4; ++cp){
      int c = cp*16 + cc;
      float4 acc = {0.f,0.f,0.f,0.f};
      #pragma unroll
      for (int s = 0; s < NSPLIT; ++s){
        float4 v = *reinterpret_cast<const float4*>(
          Opart + ((size_t)(t*NSPLIT + s)*ICH + c)*NHW + n0 + nq*4);
        acc.x += v.x; acc.y += v.y; acc.z += v.z; acc.w += v.w;
      }
      tile[nq*4+0][c] = f2bf(acc.x * zinv[nq*4+0]);
      tile[nq*4+1][c] = f2bf(acc.y * zinv[nq*4+1]);
      tile[nq*4+2][c] = f2bf(acc.z * zinv[nq*4+2]);
      tile[nq*4+3][c] = f2bf(acc.w * zinv[nq*4+3]);
    }
    __syncthreads();

    #pragma unroll
    for (int rep = 0; rep < 2; ++rep){
      int idx = rep*256 + threadIdx.x;
      int n = idx >> 3, seg = idx & 7;
      short8 v = *reinterpret_cast<short8*>(&tile[n][seg*8]);
      *reinterpret_cast<short8*>(reinterpret_cast<short*>(corrT)
          + (size_t)(n0 + n)*512 + t*64 + seg*8) = v;
    }
  } else {
    const int mbid = b - 448;
    const int n0 = mbid*32;
    const int w = threadIdx.x >> 6, lane = threadIdx.x & 63;
    const int l15 = lane & 15, quad = lane >> 4;

    const short* phi_s = reinterpret_cast<const short*>(phi_bf);
    const short* mbT_s = reinterpret_cast<const short*>(mbT);
    const short* mb_s  = reinterpret_cast<const short*>(mbbf);

    short8 Bp[2][2];
    #pragma unroll
    for (int nt = 0; nt < 2; ++nt){
      const short* pp = phi_s + (size_t)(n0 + nt*16 + l15)*ICH + quad*8;
      Bp[nt][0] = *reinterpret_cast<const short8*>(pp);
      Bp[nt][1] = *reinterpret_cast<const short8*>(pp + 32);
    }
    float psum[2] = {0.f, 0.f};
    #pragma unroll
    for (int jt = 0; jt < 4; ++jt){
      const short* ap = mbT_s + (size_t)(w*64 + jt*16 + l15)*64 + quad*8;
      short8 A0 = *reinterpret_cast<const short8*>(ap);
      short8 A1 = *reinterpret_cast<const short8*>(ap + 32);
      #pragma unroll
      for (int nt = 0; nt < 2; ++nt){
        floatx4 acc = (floatx4){0.f,0.f,0.f,0.f};
        acc = __builtin_amdgcn_mfma_f32_16x16x32_bf16(A0, Bp[nt][0], acc, 0, 0, 0);
        acc = __builtin_amdgcn_mfma_f32_16x16x32_bf16(A1, Bp[nt][1], acc, 0, 0, 0);
        sshort4 pk;
        #pragma unroll
        for (int r = 0; r < 4; ++r){
          float p = exp2f(acc[r] * (0.125f*LOG2E));
          psum[nt] += p;
          pk[r] = f2bf(p);
        }
        *reinterpret_cast<sshort4*>(&P[nt*16 + l15][w*64 + jt*16 + quad*4]) = pk;
      }
    }
    #pragma unroll
    for (int nt = 0; nt < 2; ++nt){
      float z = psum[nt];
      z += __shfl_xor(z, 16);
      z += __shfl_xor(z, 32);
      if (quad == 0) Zsh[w][nt*16 + l15] = z;
    }
    __syncthreads();

    float ql = 0.f;
    #pragma unroll
    for (int nt = 0; nt < 2; ++nt){
      floatx4 acc = (floatx4){0.f,0.f,0.f,0.f};
      #pragma unroll
      for (int kk = 0; kk < 8; ++kk){
        const short* ap = mb_s + (size_t)(w*16 + l15)*256 + kk*32 + quad*8;
        short8 A = *reinterpret_cast<const short8*>(ap);
        short8 Bv = *reinterpret_cast<const short8*>(&P[nt*16 + l15][kk*32 + quad*8]);
        acc = __builtin_amdgcn_mfma_f32_16x16x32_bf16(A, Bv, acc, 0, 0, 0);
      }
      int nn = nt*16 + l15;
      float zt = Zsh[0][nn] + Zsh[1][nn] + Zsh[2][nn] + Zsh[3][nn];
      float rz = 1.f / zt;
      const short* ph = phi_s + (size_t)(n0 + nn)*ICH + w*16 + quad*4;
      sshort4 ph4 = *reinterpret_cast<const sshort4*>(ph);
      sshort4 pk;
      #pragma unroll
      for (int r = 0; r < 4; ++r){
        float y = acc[r] * rz;
        ql += fabsf(bf2f(ph4[r]) - y);
        pk[r] = f2bf(y);
      }
      short* dst = reinterpret_cast<short*>(corrT) + (size_t)(n0 + nn)*512 + 448 + w*16 + quad*4;
      *reinterpret_cast<sshort4*>(dst) = pk;
    }
    #pragma unroll
    for (int off = 32; off; off >>= 1) ql += __shfl_xor(ql, off);
    if (lane == 0) qred[w] = ql;
    __syncthreads();
    if (threadIdx.x == 0)
      qpart[mbid] = qred[0] + qred[1] + qred[2] + qred[3];
  }
}

// ---------------- z via MFMA: out[o][n] = wzcat @ corrT^T + biasz + q; qloss write
__global__ __launch_bounds__(256) void k_z(const __hip_bfloat16* __restrict__ corrT,
    const __hip_bfloat16* __restrict__ wzcat, const float* __restrict__ biasz,
    const float* __restrict__ x, const float* __restrict__ qpart,
    float* __restrict__ out){
  const int n0 = blockIdx.x*16;
  const int w = threadIdx.x >> 6, lane = threadIdx.x & 63;
  const int l15 = lane & 15, quad = lane >> 4;
  const int o0 = blockIdx.y*64 + w*16;

  const short* ct_s = reinterpret_cast<const short*>(corrT) + (size_t)(n0 + l15)*512 + quad*8;
  const short* wz_s = reinterpret_cast<const short*>(wzcat) + (size_t)(o0 + l15)*512 + quad*8;

  floatx4 acc = (floatx4){0.f,0.f,0.f,0.f};
  #pragma unroll
  for (int kk = 0; kk < 16; ++kk){
    short8 A = *reinterpret_cast<const short8*>(wz_s + kk*32);
    short8 B = *reinterpret_cast<const short8*>(ct_s + kk*32);
    acc = __builtin_amdgcn_mfma_f32_16x16x32_bf16(A, B, acc, 0, 0, 0);
  }
  float4 bz = *reinterpret_cast<const float4*>(biasz + o0 + quad*4);
  float bzv[4] = {bz.x, bz.y, bz.z, bz.w};
  #pragma unroll
  for (int r = 0; r < 4; ++r){
    int o = o0 + quad*4 + r;
    int n = n0 + l15;
    float q = x[((size_t)3*CCH + o)*NHW + n];
    out[(size_t)o*NHW + n] = acc[r] + bzv[r] + q;
  }
  if (blockIdx.x == 0 && blockIdx.y == 0 && threadIdx.x == 0){
    float s = 0.f;
    for (int i = 0; i < 128; ++i) s += qpart[i];
    out[(size_t)CCH*NHW] = s * (1.f/262144.f);
  }
}

extern "C" void kernel_launch(void* const* d_in, const int* in_sizes, int n_in,
                              void* d_out, int out_size, void* d_ws, size_t ws_size,
                              hipStream_t stream){
  const float* x     = (const float*)d_in[0];
  const float* gamma = (const float*)d_in[1];
  const float* beta  = (const float*)d_in[2];
  const float* g_w   = (const float*)d_in[3];
  const float* g_b   = (const float*)d_in[4];
  const float* th_w  = (const float*)d_in[5];
  const float* th_b  = (const float*)d_in[6];
  const float* ph_w  = (const float*)d_in[7];
  const float* ph_b  = (const float*)d_in[8];
  const float* wz_w  = (const float*)d_in[9];
  const float* wz_b  = (const float*)d_in[10];
  const float* wz1_w = (const float*)d_in[11];
  const float* wz1_b = (const float*)d_in[12];
  const float* mb    = (const float*)d_in[13];
  const float* stdp  = (const float*)d_in[14];
  float* out = (float*)d_out;

  char* ws = (char*)d_ws;
  size_t off = 0;
  auto alloc = [&](size_t bytes)->char*{
    char* p = ws + off; off += (bytes + 255) & ~(size_t)255; return p;
  };
  float* spart   = (float*)alloc((size_t)64*224*4);
  float* spart2  = (float*)alloc((size_t)64*224*4);
  float* qpart   = (float*)alloc(128*4);
  __hip_bfloat16* xbf    = (__hip_bfloat16*)alloc((size_t)TT*NHW*CCH*2);
  __hip_bfloat16* Wth    = (__hip_bfloat16*)alloc((size_t)TT*ICH*CCH*2);
  float* bth             = (float*)alloc(TT*64*4);
  __hip_bfloat16* Wg     = (__hip_bfloat16*)alloc((size_t)TT*ICH*CCH*2);
  float* bg              = (float*)alloc(TT*64*4);
  __hip_bfloat16* Wphi   = (__hip_bfloat16*)alloc((size_t)ICH*CCH*2);
  float* bphi            = (float*)alloc(64*4);
  __hip_bfloat16* wzcat  = (__hip_bfloat16*)alloc((size_t)128*512*2);
  float* biasz           = (float*)alloc(128*4);
  __hip_bfloat16* mbT    = (__hip_bfloat16*)alloc((size_t)256*64*2);
  __hip_bfloat16* mbbf   = (__hip_bfloat16*)alloc((size_t)64*256*2);
  __hip_bfloat16* thetaT = (__hip_bfloat16*)alloc((size_t)TT*NHW*ICH*2);
  __hip_bfloat16* g_nat  = (__hip_bfloat16*)alloc((size_t)TT*NHW*ICH*2);
  __hip_bfloat16* phi_bf = (__hip_bfloat16*)alloc((size_t)NHW*ICH*2);
  __hip_bfloat16* corrT  = (__hip_bfloat16*)alloc((size_t)NHW*512*2);
  float* Opart   = (float*)alloc((size_t)TT*NSPLIT*ICH*NHW*4);
  float* Zpart   = (float*)alloc((size_t)TT*NSPLIT*NHW*4);

  k_precast<<<dim3(64,7,2), 256, 0, stream>>>(x, xbf, spart, spart2);
  k_setup<<<368, 256, 0, stream>>>(g_w, g_b, th_w, th_b, ph_w, ph_b, gamma, beta,
                                   spart, spart2, Wth, bth, Wg, bg, Wphi, bphi,
                                   wz_w, wz1_w, wz_b, wz1_b, mb, wzcat, biasz, mbT, mbbf);
  k_conv<<<dim3(64,7,2), 256, 0, stream>>>(xbf, Wth, bth, Wg, bg, Wphi, bphi,
                                           thetaT, g_nat, phi_bf);
  k_attn<<<dim3(64,NSPLIT,7), 256, 0, stream>>>(phi_bf, thetaT, g_nat, stdp, Opart, Zpart);
  k_post<<<576, 256, 0, stream>>>(Opart, Zpart, phi_bf, mbT, mbbf, corrT, qpart);
  k_z   <<<dim3(256,2), 256, 0, stream>>>(corrT, wzcat, biasz, x, qpart, out);
}